// Round 2
// baseline (389.829 us; speedup 1.0000x reference)
//
#include <hip/hip_runtime.h>

#define B_SZ 2
#define E_SZ 1024
#define C_SZ 128
#define R_REL 32
#define TS 64
#define TO 64

typedef float f32x4 __attribute__((ext_vector_type(4)));

// G lives in a static device buffer: no workspace dependency, no fallback
// ambiguity. 8 MiB. Fully overwritten by gram_tile before scale_stream
// reads it (same stream -> serialized; kernel-boundary release/acquire
// handles cross-XCD visibility).
__device__ float g_G[(size_t)B_SZ * E_SZ * E_SZ];

// ---------------------------------------------------------------------------
// K1: Gram tiles. G[b,s,o] = sum_c x[b,s,c] * x[b,o,c]
// Same staging + accumulation order as the verified fused kernel.
// 512 blocks, ~12 us.
// ---------------------------------------------------------------------------
__global__ __launch_bounds__(256, 2) void gram_tile(
        const float* __restrict__ x) {
    __shared__ float xs[TS][C_SZ + 4];
    __shared__ float xo[TO][C_SZ + 4];

    const int b  = blockIdx.z;
    const int s0 = blockIdx.y * TS;
    const int o0 = blockIdx.x * TO;
    const int tid = threadIdx.x;

    const float4* src_s = (const float4*)(x + (size_t)b * E_SZ * C_SZ + (size_t)s0 * C_SZ);
    const float4* src_o = (const float4*)(x + (size_t)b * E_SZ * C_SZ + (size_t)o0 * C_SZ);
    #pragma unroll
    for (int i = tid; i < TS * (C_SZ / 4); i += 256) {
        const int row = i >> 5;
        const int col = (i & 31) << 2;
        *(float4*)&xs[row][col] = src_s[i];
        *(float4*)&xo[row][col] = src_o[i];
    }
    __syncthreads();

    const int tx = tid & 15;
    const int ty = tid >> 4;
    const int si = ty << 2;
    const int oj = tx << 2;

    float acc[4][4];
    #pragma unroll
    for (int ii = 0; ii < 4; ++ii)
        #pragma unroll
        for (int jj = 0; jj < 4; ++jj) acc[ii][jj] = 0.f;

    #pragma unroll 4
    for (int c = 0; c < C_SZ; c += 4) {
        float4 a[4], bb[4];
        #pragma unroll
        for (int ii = 0; ii < 4; ++ii) a[ii]  = *(const float4*)&xs[si + ii][c];
        #pragma unroll
        for (int jj = 0; jj < 4; ++jj) bb[jj] = *(const float4*)&xo[oj + jj][c];
        #pragma unroll
        for (int ii = 0; ii < 4; ++ii) {
            #pragma unroll
            for (int jj = 0; jj < 4; ++jj) {
                acc[ii][jj] += a[ii].x * bb[jj].x + a[ii].y * bb[jj].y
                             + a[ii].z * bb[jj].z + a[ii].w * bb[jj].w;
            }
        }
    }

    #pragma unroll
    for (int ii = 0; ii < 4; ++ii) {
        float4 gv;
        gv.x = acc[ii][0]; gv.y = acc[ii][1]; gv.z = acc[ii][2]; gv.w = acc[ii][3];
        *(float4*)(g_G + ((size_t)b * E_SZ + (size_t)(s0 + si + ii)) * E_SZ + o0 + oj) = gv;
    }
}

// ---------------------------------------------------------------------------
// K2: pure stream. out[b,s,r,o] = G[b,s,o] * R[r,s,o]
// Block = (s, r-chunk of 16); thread t owns float4 column o4 = t for BOTH
// batches -> each R element fetched exactly once from HBM (134 MB not 268).
// Plain float4 loads/stores (no NT flags — the 6.4 TB/s fill uses plain
// stores; NT is unverified on gfx950 and was the prime suspect).
// No LDS, small VGPR footprint -> 8 blocks/CU = 32 waves/CU; grid 2048 =
// exactly one full-residency pass.
// ---------------------------------------------------------------------------
__global__ __launch_bounds__(256, 8) void scale_stream(
        const float* __restrict__ R,
        float* __restrict__ out) {
    const int o4 = threadIdx.x;               // float4 column 0..255
    const int s  = blockIdx.x;                // 0..1023
    const int r0 = blockIdx.y * (R_REL / 2);  // 0 or 16

    const f32x4* G4 = (const f32x4*)g_G;
    const f32x4* R4 = (const f32x4*)R;
    f32x4*       O4 = (f32x4*)out;

    const f32x4 g0 = G4[(size_t)s * (E_SZ / 4) + o4];
    const f32x4 g1 = G4[((size_t)E_SZ + s) * (E_SZ / 4) + o4];

    const f32x4* rp  = R4 + ((size_t)r0 * E_SZ + s) * (E_SZ / 4) + o4;
    f32x4*       op0 = O4 + (((size_t)s) * R_REL + r0) * (E_SZ / 4) + o4;
    f32x4*       op1 = O4 + (((size_t)(E_SZ + s)) * R_REL + r0) * (E_SZ / 4) + o4;

    #pragma unroll 4
    for (int r = 0; r < R_REL / 2; ++r) {
        const f32x4 rv = rp[(size_t)r * (E_SZ * E_SZ / 4)];
        op0[(size_t)r * (E_SZ / 4)] = rv * g0;
        op1[(size_t)r * (E_SZ / 4)] = rv * g1;
    }
}

extern "C" void kernel_launch(void* const* d_in, const int* in_sizes, int n_in,
                              void* d_out, int out_size, void* d_ws, size_t ws_size,
                              hipStream_t stream) {
    const float* x = (const float*)d_in[0];
    const float* R = (const float*)d_in[1];
    float* out = (float*)d_out;

    dim3 g1(E_SZ / TO, E_SZ / TS, B_SZ);   // 512 blocks
    gram_tile<<<g1, 256, 0, stream>>>(x);
    dim3 g2(E_SZ, R_REL / 16);             // 2048 blocks
    scale_stream<<<g2, 256, 0, stream>>>(R, out);
}